// Round 2
// baseline (60.311 us; speedup 1.0000x reference)
//
#include <hip/hip_runtime.h>
#include <hip/hip_bf16.h>
#include <hip/hip_fp16.h>

#define K_DIM 4096
#define N_DIM 14336
#define B_M   32
#define KSPLIT 4
#define NSTEPS 128                 // K_DIM / 32
#define STEPS_PER (NSTEPS / KSPLIT)
#define NTILES (N_DIM / 16)        // 896

typedef __attribute__((ext_vector_type(8))) short short8;
typedef __attribute__((ext_vector_type(4))) float f32x4;
typedef __attribute__((ext_vector_type(4))) int   i32x4;

static __device__ __forceinline__ short f2bf(float f) {
    union { float f; unsigned u; } v; v.f = f;
    unsigned r = v.u + 0x7FFFu + ((v.u >> 16) & 1u);   // RNE to bf16
    return (short)(r >> 16);
}

// Pre-swizzle x (32x4096 f32) into MFMA A-fragment order, bf16.
// Layout: xa[((s*2+f)*64 + lane)*8 + j] = bf16(x[16*f + (lane&15)][32*s + 8*(lane>>4) + j])
__global__ __launch_bounds__(256) void prep_xa_kernel(const float* __restrict__ x,
                                                      short* __restrict__ xa) {
    int t = blockIdx.x * 256 + threadIdx.x;   // 0 .. 131071
    int j = t & 7;
    int l = (t >> 3) & 63;
    int f = (t >> 9) & 1;
    int s = t >> 10;                          // 0 .. 127
    int m = 16 * f + (l & 15);
    int k = 32 * s + 8 * (l >> 4) + j;
    xa[t] = f2bf(x[(size_t)m * K_DIM + k]);
}

template<bool SPLIT, bool USE_XA>
__global__ __launch_bounds__(64) void gemm_kernel(
        const int* __restrict__ qw, const short* __restrict__ xa,
        const float* __restrict__ x,
        const float* __restrict__ scales, const float* __restrict__ bias,
        float* __restrict__ outp) {
    const int lane = threadIdx.x;             // 0..63, one wave per block
    const int g = lane >> 4;                  // k-group 0..3
    const int n = blockIdx.x * 16 + (lane & 15);
    const int kslice = SPLIT ? blockIdx.y : 0;
    const int s0 = kslice * (SPLIT ? STEPS_PER : NSTEPS);
    const int send = s0 + (SPLIT ? STEPS_PER : NSTEPS);

    const int* qrow = qw + (size_t)n * K_DIM + 8 * g;
    const float* srow = scales + (size_t)n * (K_DIM / 64);   // scales delivered as f32

    f32x4 acc0 = {0.f, 0.f, 0.f, 0.f};
    f32x4 acc1 = {0.f, 0.f, 0.f, 0.f};

    // prefetch first K-step's q + scale
    i32x4 qa = *(const i32x4*)(qrow + 32 * s0);
    i32x4 qb = *(const i32x4*)(qrow + 32 * s0 + 4);
    float sc = srow[s0 >> 1];

    #pragma unroll 4
    for (int s = s0; s < send; ++s) {
        int sn = s + 1; if (sn > NSTEPS - 1) sn = NSTEPS - 1;   // clamp: stay in-bounds
        i32x4 nqa = *(const i32x4*)(qrow + 32 * sn);
        i32x4 nqb = *(const i32x4*)(qrow + 32 * sn + 4);
        float nsc = srow[sn >> 1];

        // A fragments (m 0..15 and 16..31), k-slot (g,j) <-> k = 8g+j
        short8 a0, a1;
        if (USE_XA) {
            a0 = *(const short8*)(xa + (size_t)s * 1024 + lane * 8);
            a1 = *(const short8*)(xa + (size_t)s * 1024 + 512 + lane * 8);
        } else {
            const float* xr0 = x + (size_t)(lane & 15) * K_DIM + 32 * s + 8 * g;
            const float* xr1 = xr0 + 16 * K_DIM;
            f32x4 x00 = *(const f32x4*)xr0, x01 = *(const f32x4*)(xr0 + 4);
            f32x4 x10 = *(const f32x4*)xr1, x11 = *(const f32x4*)(xr1 + 4);
            #pragma unroll
            for (int j = 0; j < 4; ++j) { a0[j] = f2bf(x00[j]); a0[j + 4] = f2bf(x01[j]); }
            #pragma unroll
            for (int j = 0; j < 4; ++j) { a1[j] = f2bf(x10[j]); a1[j + 4] = f2bf(x11[j]); }
        }

        // dequant B fragment: w[n][32s + 8g + j] = q * scale, same (g,j)->k map as A
        short8 bw;
        bw[0] = f2bf((float)qa[0] * sc);
        bw[1] = f2bf((float)qa[1] * sc);
        bw[2] = f2bf((float)qa[2] * sc);
        bw[3] = f2bf((float)qa[3] * sc);
        bw[4] = f2bf((float)qb[0] * sc);
        bw[5] = f2bf((float)qb[1] * sc);
        bw[6] = f2bf((float)qb[2] * sc);
        bw[7] = f2bf((float)qb[3] * sc);

        acc0 = __builtin_amdgcn_mfma_f32_16x16x32_bf16(a0, bw, acc0, 0, 0, 0);
        acc1 = __builtin_amdgcn_mfma_f32_16x16x32_bf16(a1, bw, acc1, 0, 0, 0);

        qa = nqa; qb = nqb; sc = nsc;
    }

    // C/D layout (verified): col = lane&15 (n), row = 4*(lane>>4)+r (b)
    if (SPLIT) {
        float* pp = outp + (size_t)kslice * B_M * N_DIM + n;
        #pragma unroll
        for (int r = 0; r < 4; ++r) {
            pp[(size_t)(4 * g + r) * N_DIM]      = acc0[r];
            pp[(size_t)(16 + 4 * g + r) * N_DIM] = acc1[r];
        }
    } else {
        float bv = bias[n];
        float* pp = outp + n;
        #pragma unroll
        for (int r = 0; r < 4; ++r) {
            pp[(size_t)(4 * g + r) * N_DIM]      = acc0[r] + bv;
            pp[(size_t)(16 + 4 * g + r) * N_DIM] = acc1[r] + bv;
        }
    }
}

__global__ __launch_bounds__(256) void reduce_kernel(const f32x4* __restrict__ part,
                                                     const f32x4* __restrict__ bias4,
                                                     f32x4* __restrict__ out4) {
    int i = blockIdx.x * 256 + threadIdx.x;   // 0 .. 114687 (32*14336/4)
    int b = i / (N_DIM / 4);
    int nq = i - b * (N_DIM / 4);
    f32x4 s = bias4[nq];
    #pragma unroll
    for (int ks = 0; ks < KSPLIT; ++ks)
        s += part[((size_t)(ks * B_M + b)) * (N_DIM / 4) + nq];
    out4[i] = s;
}

extern "C" void kernel_launch(void* const* d_in, const int* in_sizes, int n_in,
                              void* d_out, int out_size, void* d_ws, size_t ws_size,
                              hipStream_t stream) {
    const float* x    = (const float*)d_in[0];
    const int*   qw   = (const int*)d_in[1];
    const float* sc   = (const float*)d_in[2];   // fp16 in reference, delivered as f32
    const float* bias = (const float*)d_in[3];
    float* out = (float*)d_out;

    const size_t XA_BYTES   = (size_t)B_M * K_DIM * 2;            // 262144
    const size_t PART_BYTES = (size_t)KSPLIT * B_M * N_DIM * 4;   // 7340032

    bool have_xa   = ws_size >= XA_BYTES;
    bool have_part = ws_size >= XA_BYTES + PART_BYTES;

    short* xa   = (short*)d_ws;
    float* part = (float*)((char*)d_ws + XA_BYTES);

    if (have_xa)
        prep_xa_kernel<<<dim3(512), dim3(256), 0, stream>>>(x, xa);

    if (have_xa && have_part) {
        gemm_kernel<true, true><<<dim3(NTILES, KSPLIT), dim3(64), 0, stream>>>(
            qw, xa, x, sc, bias, part);
        reduce_kernel<<<dim3((B_M * N_DIM / 4) / 256), dim3(256), 0, stream>>>(
            (const f32x4*)part, (const f32x4*)bias, (f32x4*)out);
    } else if (have_xa) {
        gemm_kernel<false, true><<<dim3(NTILES, 1), dim3(64), 0, stream>>>(
            qw, xa, x, sc, bias, out);
    } else {
        gemm_kernel<false, false><<<dim3(NTILES, 1), dim3(64), 0, stream>>>(
            qw, xa, x, sc, bias, out);
    }
}